// Round 1
// 3887.680 us; speedup vs baseline: 1.7094x; 1.7094x over previous
//
#include <hip/hip_runtime.h>
#include <hip/hip_bf16.h>
#include <cstdint>
#include <cstddef>

#define LNUM 12
#define NH 12
#define CDIM 768
#define HDIM 64
#define TSEQ 1024
#define BSZ 2
#define MROWS 2048   // B*T
#define VOCAB 50257

typedef __attribute__((ext_vector_type(8))) short short8;
typedef __attribute__((ext_vector_type(4))) float f32x4;
typedef __attribute__((ext_vector_type(2))) unsigned int u32x2;
typedef unsigned short u16;
typedef unsigned int u32;

__device__ __forceinline__ u16 f2bu(float f) {
  __hip_bfloat16 h = __float2bfloat16(f);
  return *reinterpret_cast<u16*>(&h);
}

// async global->LDS, 16B per lane; LDS dest = wave-uniform base + lane*16
__device__ __forceinline__ void gl_lds16(const void* g, void* l) {
  __builtin_amdgcn_global_load_lds(
      (const __attribute__((address_space(1))) unsigned int*)g,
      (__attribute__((address_space(3))) unsigned int*)l,
      16, 0, 0);
}

// ---------------- embedding: x = wte[idx] + wpe[t] ----------------
__global__ __launch_bounds__(256)
void embed_kernel(const int* __restrict__ idx,
                  const float* __restrict__ wte,
                  const float* __restrict__ wpe,
                  float* __restrict__ x) {
  int row = blockIdx.x;            // 0..2047  (b*T + t)
  int t = row & (TSEQ - 1);
  int id = idx[row];
  const float* we = wte + (size_t)id * CDIM;
  const float* wp = wpe + (size_t)t * CDIM;
  float* xr = x + (size_t)row * CDIM;
  for (int c = threadIdx.x; c < CDIM; c += 256)
    xr[c] = we[c] + wp[c];
}

// ---------------- layernorm: fp32 in -> bf16 out ----------------
__global__ __launch_bounds__(256)
void ln_kernel(const float* __restrict__ x, const float* __restrict__ w,
               const float* __restrict__ b, __hip_bfloat16* __restrict__ out) {
  int row = blockIdx.x;
  int tid = threadIdx.x;
  const float* xr = x + (size_t)row * CDIM;
  float v0 = xr[tid], v1 = xr[tid + 256], v2 = xr[tid + 512];
  float s = v0 + v1 + v2;
  float ss = v0 * v0 + v1 * v1 + v2 * v2;
#pragma unroll
  for (int off = 32; off > 0; off >>= 1) {
    s += __shfl_xor(s, off, 64);
    ss += __shfl_xor(ss, off, 64);
  }
  __shared__ float red[8];
  int lane = tid & 63, wid = tid >> 6;
  if (lane == 0) { red[wid] = s; red[4 + wid] = ss; }
  __syncthreads();
  s = red[0] + red[1] + red[2] + red[3];
  ss = red[4] + red[5] + red[6] + red[7];
  float mu = s * (1.f / CDIM);
  float var = ss * (1.f / CDIM) - mu * mu;
  float rstd = rsqrtf(var + 1e-5f);
  __hip_bfloat16* orow = out + (size_t)row * CDIM;
  orow[tid]       = __float2bfloat16((v0 - mu) * rstd * w[tid]       + b[tid]);
  orow[tid + 256] = __float2bfloat16((v1 - mu) * rstd * w[tid + 256] + b[tid + 256]);
  orow[tid + 512] = __float2bfloat16((v2 - mu) * rstd * w[tid + 512] + b[tid + 512]);
}

// ------- weight transpose+convert: fp32 W[K,N] -> bf16 Wt[N,K] -------
__global__ __launch_bounds__(256)
void convT_kernel(const float* __restrict__ W, __hip_bfloat16* __restrict__ Wt,
                  int K, int N) {
  __shared__ float tile[32][33];
  int n0 = blockIdx.x * 32;
  int k0 = blockIdx.y * 32;
  int tx = threadIdx.x & 31;
  int ty = threadIdx.x >> 5;  // 0..7
#pragma unroll
  for (int i = 0; i < 4; i++) {
    int k = k0 + ty + i * 8;
    int n = n0 + tx;
    float v = 0.f;
    if (k < K && n < N) v = W[(size_t)k * N + n];
    tile[ty + i * 8][tx] = v;
  }
  __syncthreads();
#pragma unroll
  for (int i = 0; i < 4; i++) {
    int n = n0 + ty + i * 8;
    int k = k0 + tx;
    if (n < N && k < K)
      Wt[(size_t)n * K + k] = __float2bfloat16(tile[tx][ty + i * 8]);
  }
}

// ---------------- MFMA GEMM: C[M,N] = A[M,K] @ Wt[N,K]^T + bias ----------------
// 1-D grid = nnb*16 blocks; bijective XCD swizzle, m-fastest within each XCD
// so consecutive blocks on one XCD share the same Wt panel (L2 reuse).
// MODE 1: gelu -> bf16 out_b      MODE 2: out_f += val (fp32 residual)
// MODE 3: qkv scatter -> bf16 Qb([bh][t][d], pre-scaled 1/8), Kb([bh][t][d]), Vt([bh][d][t])
// MODE 4: raw fp32 out_f (no bias)
template <int MODE>
__global__ __launch_bounds__(256)
void gemm_kernel(const __hip_bfloat16* __restrict__ A,
                 const __hip_bfloat16* __restrict__ Wt,
                 const float* __restrict__ bias,
                 int K, int N,
                 float* __restrict__ out_f,
                 __hip_bfloat16* __restrict__ out_b,
                 __hip_bfloat16* __restrict__ Qb,
                 __hip_bfloat16* __restrict__ Kb,
                 __hip_bfloat16* __restrict__ Vt) {
  __shared__ short a_sh[128 * 32];
  __shared__ short b_sh[128 * 32];
  int tid = threadIdx.x;
  int lane = tid & 63;
  int wv = tid >> 6;

  // bijective XCD swizzle (m204); all grids here are %8==0 but keep general.
  int nwg = (int)gridDim.x;
  int orig = (int)blockIdx.x;
  int q8 = nwg >> 3, r8 = nwg & 7;
  int xcd = orig & 7, loc = orig >> 3;
  int swz = (xcd < r8 ? xcd * (q8 + 1) : r8 * (q8 + 1) + (xcd - r8) * q8) + loc;
  int m0 = (swz & 15) * 128;   // M == 2048 always -> 16 m-blocks, m fastest
  int n0 = (swz >> 4) * 128;

  int wm = (wv >> 1) * 64, wn = (wv & 1) * 64;

  f32x4 acc[4][4];
  f32x4 zero4 = {0.f, 0.f, 0.f, 0.f};
#pragma unroll
  for (int i = 0; i < 4; i++)
#pragma unroll
    for (int j = 0; j < 4; j++) acc[i][j] = zero4;

  const short* Ap = (const short*)A;
  const short* Wp = (const short*)Wt;

  // staging geometry: per wave 2x16-row chunks of A and B, 16B/lane
  int ls_row = lane >> 2;          // 0..15
  int ls_col = (lane & 3) * 8;     // shorts
  int nr0 = n0 + wv * 32 + ls_row;
  int nr1 = nr0 + 16;
  if (nr0 > N - 1) nr0 = N - 1;    // clamp (lm_head edge); masked in epilogue
  if (nr1 > N - 1) nr1 = N - 1;
  const short* agb = Ap + (size_t)(m0 + wv * 32 + ls_row) * K + ls_col;
  const short* bg0 = Wp + (size_t)nr0 * K + ls_col;
  const short* bg1 = Wp + (size_t)nr1 * K + ls_col;

  for (int k0 = 0; k0 < K; k0 += 32) {
    // async stage A,B tiles [128 x 32] via global_load_lds (wave-linear LDS)
    gl_lds16(agb + k0, &a_sh[(wv * 32) * 32]);
    gl_lds16(agb + k0 + (size_t)16 * K, &a_sh[(wv * 32 + 16) * 32]);
    gl_lds16(bg0 + k0, &b_sh[(wv * 32) * 32]);
    gl_lds16(bg1 + k0, &b_sh[(wv * 32 + 16) * 32]);
    __syncthreads();   // compiler drains vmcnt(0) before s_barrier
    // compute: 4x4 of 16x16x32 MFMA per wave (64x64 per wave)
    int arow = wm + (lane & 15);
    int brow = wn + (lane & 15);
    int kq = (lane >> 4) * 8;
    short8 af[4], bf[4];
#pragma unroll
    for (int i = 0; i < 4; i++) {
      af[i] = *(const short8*)(&a_sh[(arow + i * 16) * 32 + kq]);
      bf[i] = *(const short8*)(&b_sh[(brow + i * 16) * 32 + kq]);
    }
#pragma unroll
    for (int i = 0; i < 4; i++)
#pragma unroll
      for (int j = 0; j < 4; j++)
        acc[i][j] = __builtin_amdgcn_mfma_f32_16x16x32_bf16(af[i], bf[j], acc[i][j], 0, 0, 0);
    __syncthreads();
  }

  // epilogue: C/D layout (verified m89): col = lane&15, row = (lane>>4)*4 + r
  int row0 = (lane >> 4) * 4;
  int col0 = lane & 15;
#pragma unroll
  for (int i = 0; i < 4; i++) {
#pragma unroll
    for (int j = 0; j < 4; j++) {
#pragma unroll
      for (int r = 0; r < 4; r++) {
        int m = m0 + wm + i * 16 + row0 + r;
        int n = n0 + wn + j * 16 + col0;
        if (n >= N) continue;
        float val = acc[i][j][r];
        if (MODE != 4) val += bias[n];
        if (MODE == 1) {
          float u = val;
          float g = 0.5f * u * (1.f + tanhf(0.7978845608028654f * (u + 0.044715f * u * u * u)));
          out_b[(size_t)m * N + n] = __float2bfloat16(g);
        } else if (MODE == 2) {
          out_f[(size_t)m * N + n] += val;
        } else if (MODE == 3) {
          int b_ = m >> 10, t = m & 1023;
          if (n < 768) {
            int h = n >> 6, d = n & 63;
            Qb[(((size_t)(b_ * NH + h)) * TSEQ + t) * HDIM + d] = __float2bfloat16(val * 0.125f);
          } else if (n < 1536) {
            int u2 = n - 768;
            int h = u2 >> 6, d = u2 & 63;
            Kb[(((size_t)(b_ * NH + h)) * TSEQ + t) * HDIM + d] = __float2bfloat16(val);
          } else {
            int u2 = n - 1536;
            int h = u2 >> 6, d = u2 & 63;
            Vt[(((size_t)(b_ * NH + h)) * HDIM + d) * TSEQ + t] = __float2bfloat16(val);
          }
        } else {  // MODE 4
          out_f[(size_t)m * (size_t)N + n] = val;
        }
      }
    }
  }
}

// ---------------- MFMA flash attention ----------------
// block = 256 thr (4 waves) per (bh, 64-row q-tile). Wave w owns q rows
// q0+w*16..+15. Per kv-tile (64 keys): S^T = mfma(K,Q) so the row-softmax is a
// 4-lane xor-shuffle reduce; P->bf16 through wave-private LDS; O += mfma(P,V^T).
// Online softmax (m,l) kept in stat layout (lane&15 = q), O in C layout.
__global__ __launch_bounds__(256)
void attn_kernel(const __hip_bfloat16* __restrict__ Qb,
                 const __hip_bfloat16* __restrict__ Kb,
                 const __hip_bfloat16* __restrict__ Vt,
                 __hip_bfloat16* __restrict__ y) {
  __shared__ u16 k_sh[64][72];     // K tile  [kc][d], pad 72 -> 2-way max
  __shared__ u16 vt_sh[64][72];    // V^T tile [d][kc]
  __shared__ u16 p_sh[4][16][72];  // per-wave P [q][kc] bf16
  int tid = threadIdx.x;
  int lane = tid & 63, wv = tid >> 6;
  int qt = (int)gridDim.x - 1 - (int)blockIdx.x;  // long chains first
  int bh = blockIdx.y;
  int q0 = qt * 64;
  const u16* Kp = (const u16*)Kb + (size_t)bh * TSEQ * HDIM;
  const u16* Vp = (const u16*)Vt + (size_t)bh * HDIM * TSEQ;
  int lq = lane & 15;   // stat-layout q column
  int lh = lane >> 4;   // 0..3

  // Q B-frags held across the kv loop (row q0+wv*16+lq, k = d)
  const u16* Qp = (const u16*)Qb + ((size_t)bh * TSEQ + q0 + wv * 16 + lq) * HDIM;
  short8 qf0 = *(const short8*)(Qp + lh * 8);
  short8 qf1 = *(const short8*)(Qp + 32 + lh * 8);

  f32x4 z4 = {0.f, 0.f, 0.f, 0.f};
  f32x4 accO[4];
  accO[0] = z4; accO[1] = z4; accO[2] = z4; accO[3] = z4;
  float mrun = -1e30f, lrun = 0.f;
  int qglob = q0 + wv * 16 + lq;

  for (int kt = 0; kt <= qt; kt++) {
    int t0 = kt * 64;
    __syncthreads();                    // all waves done reading k/vt
    // stage K[64][64] and V^T[64][64] (bf16, coalesced 16B chunks)
#pragma unroll
    for (int i = 0; i < 2; i++) {
      int cc = tid + i * 256;
      int row = cc >> 3, c8 = (cc & 7) * 8;
      *(short8*)&k_sh[row][c8]  = *(const short8*)(Kp + (size_t)(t0 + row) * HDIM + c8);
      *(short8*)&vt_sh[row][c8] = *(const short8*)(Vp + (size_t)row * TSEQ + t0 + c8);
    }
    __syncthreads();

    // S^T[kc][q] = K . Q^T : 4 kc-tiles x 2 k-steps
    f32x4 accS[4];
    accS[0] = z4; accS[1] = z4; accS[2] = z4; accS[3] = z4;
#pragma unroll
    for (int t = 0; t < 4; t++) {
      short8 kf0 = *(const short8*)&k_sh[t * 16 + lq][lh * 8];
      short8 kf1 = *(const short8*)&k_sh[t * 16 + lq][32 + lh * 8];
      accS[t] = __builtin_amdgcn_mfma_f32_16x16x32_bf16(kf0, qf0, accS[t], 0, 0, 0);
      accS[t] = __builtin_amdgcn_mfma_f32_16x16x32_bf16(kf1, qf1, accS[t], 0, 0, 0);
    }

    // causal mask + tile max (lane holds kc = t0+16t+4*lh+r for column q=lq)
    float sv[4][4];
    float mtile = -1e30f;
#pragma unroll
    for (int t = 0; t < 4; t++)
#pragma unroll
      for (int r = 0; r < 4; r++) {
        float s = accS[t][r];
        int kcg = t0 + t * 16 + lh * 4 + r;
        s = (kcg <= qglob) ? s : -1e30f;
        sv[t][r] = s;
        mtile = fmaxf(mtile, s);
      }
    mtile = fmaxf(mtile, __shfl_xor(mtile, 16, 64));
    mtile = fmaxf(mtile, __shfl_xor(mtile, 32, 64));
    float mnew = fmaxf(mrun, mtile);
    float scl = __expf(mrun - mnew);
    mrun = mnew;

    float psum = 0.f;
#pragma unroll
    for (int t = 0; t < 4; t++) {
      float p0 = __expf(sv[t][0] - mnew);
      float p1 = __expf(sv[t][1] - mnew);
      float p2 = __expf(sv[t][2] - mnew);
      float p3 = __expf(sv[t][3] - mnew);
      psum += (p0 + p1) + (p2 + p3);
      u32x2 pk;
      pk.x = (u32)f2bu(p0) | ((u32)f2bu(p1) << 16);
      pk.y = (u32)f2bu(p2) | ((u32)f2bu(p3) << 16);
      *(u32x2*)&p_sh[wv][lq][t * 16 + lh * 4] = pk;
    }
    psum += __shfl_xor(psum, 16, 64);
    psum += __shfl_xor(psum, 32, 64);
    lrun = lrun * scl + psum;

    // rescale O (C layout: row = lh*4+r); scale lives in stat lanes 0..15
#pragma unroll
    for (int r = 0; r < 4; r++) {
      float sr = __shfl(scl, lh * 4 + r, 64);
      accO[0][r] *= sr; accO[1][r] *= sr; accO[2][r] *= sr; accO[3][r] *= sr;
    }

    // O += P . V : A-frag P[q][kc] from p_sh, B-frag V^T[d][kc] from vt_sh
#pragma unroll
    for (int ks = 0; ks < 2; ks++) {
      short8 pf = *(const short8*)&p_sh[wv][lq][ks * 32 + lh * 8];
#pragma unroll
      for (int dt = 0; dt < 4; dt++) {
        short8 vf = *(const short8*)&vt_sh[dt * 16 + lq][ks * 32 + lh * 8];
        accO[dt] = __builtin_amdgcn_mfma_f32_16x16x32_bf16(pf, vf, accO[dt], 0, 0, 0);
      }
    }
  }

  // epilogue: O[row][d] / l_run[row] -> y bf16
  int b_ = bh / NH, h = bh - b_ * NH;
#pragma unroll
  for (int r = 0; r < 4; r++) {
    float li = __shfl(lrun, lh * 4 + r, 64);
    float linv = 1.f / li;
    int qg2 = q0 + wv * 16 + lh * 4 + r;
    __hip_bfloat16* yp = y + ((size_t)(b_ * TSEQ + qg2)) * CDIM + h * HDIM + lq;
#pragma unroll
    for (int dt = 0; dt < 4; dt++)
      yp[dt * 16] = __float2bfloat16(accO[dt][r] * linv);
  }
}

extern "C" void kernel_launch(void* const* d_in, const int* in_sizes, int n_in,
                              void* d_out, int out_size, void* d_ws, size_t ws_size,
                              hipStream_t stream) {
  (void)in_sizes; (void)n_in; (void)out_size;
  const int* idx       = (const int*)d_in[0];
  const float* wte     = (const float*)d_in[1];
  const float* wpe     = (const float*)d_in[2];
  const float* ln1_w   = (const float*)d_in[3];
  const float* ln1_b   = (const float*)d_in[4];
  const float* attn_w  = (const float*)d_in[5];
  const float* attn_b  = (const float*)d_in[6];
  const float* proj_w  = (const float*)d_in[7];
  const float* proj_b  = (const float*)d_in[8];
  const float* ln2_w   = (const float*)d_in[9];
  const float* ln2_b   = (const float*)d_in[10];
  const float* fc_w    = (const float*)d_in[11];
  const float* fc_b    = (const float*)d_in[12];
  const float* fcproj_w = (const float*)d_in[13];
  const float* fcproj_b = (const float*)d_in[14];
  const float* lnf_w   = (const float*)d_in[15];
  const float* lnf_b   = (const float*)d_in[16];
  const float* lm_head_w = (const float*)d_in[17];
  float* out = (float*)d_out;

  char* ws = (char*)d_ws;
  size_t off = 0;
  auto alloc = [&](size_t bytes) {
    char* p = ws + off;
    off = (off + bytes + 255) & ~(size_t)255;
    return p;
  };
  float* x            = (float*)alloc((size_t)MROWS * CDIM * 4);
  __hip_bfloat16* xb  = (__hip_bfloat16*)alloc((size_t)MROWS * CDIM * 2);
  __hip_bfloat16* Qb  = (__hip_bfloat16*)alloc((size_t)MROWS * CDIM * 2);
  __hip_bfloat16* Kb  = (__hip_bfloat16*)alloc((size_t)MROWS * CDIM * 2);
  __hip_bfloat16* Vt  = (__hip_bfloat16*)alloc((size_t)MROWS * CDIM * 2);
  __hip_bfloat16* yb  = (__hip_bfloat16*)alloc((size_t)MROWS * CDIM * 2);
  __hip_bfloat16* hb  = (__hip_bfloat16*)alloc((size_t)MROWS * 4 * CDIM * 2);
  __hip_bfloat16* Wt  = (__hip_bfloat16*)alloc((size_t)VOCAB * CDIM * 2);
  if (off > ws_size) return;  // workspace too small — fail loudly via wrong output

  dim3 blk(256);
  embed_kernel<<<MROWS, blk, 0, stream>>>(idx, wte, wpe, x);

  for (int l = 0; l < LNUM; l++) {
    // attn block
    ln_kernel<<<MROWS, blk, 0, stream>>>(x, ln1_w + l * CDIM, ln1_b + l * CDIM, xb);
    convT_kernel<<<dim3((3 * CDIM) / 32, CDIM / 32), blk, 0, stream>>>(
        attn_w + (size_t)l * CDIM * 3 * CDIM, Wt, CDIM, 3 * CDIM);
    gemm_kernel<3><<<dim3(((3 * CDIM) / 128) * 16), blk, 0, stream>>>(
        xb, Wt, attn_b + l * 3 * CDIM, CDIM, 3 * CDIM,
        nullptr, nullptr, Qb, Kb, Vt);
    attn_kernel<<<dim3(TSEQ / 64, BSZ * NH), blk, 0, stream>>>(Qb, Kb, Vt, yb);
    convT_kernel<<<dim3(CDIM / 32, CDIM / 32), blk, 0, stream>>>(
        proj_w + (size_t)l * CDIM * CDIM, Wt, CDIM, CDIM);
    gemm_kernel<2><<<dim3((CDIM / 128) * 16), blk, 0, stream>>>(
        yb, Wt, proj_b + l * CDIM, CDIM, CDIM,
        x, nullptr, nullptr, nullptr, nullptr);
    // mlp block
    ln_kernel<<<MROWS, blk, 0, stream>>>(x, ln2_w + l * CDIM, ln2_b + l * CDIM, xb);
    convT_kernel<<<dim3((4 * CDIM) / 32, CDIM / 32), blk, 0, stream>>>(
        fc_w + (size_t)l * CDIM * 4 * CDIM, Wt, CDIM, 4 * CDIM);
    gemm_kernel<1><<<dim3(((4 * CDIM) / 128) * 16), blk, 0, stream>>>(
        xb, Wt, fc_b + l * 4 * CDIM, CDIM, 4 * CDIM,
        nullptr, hb, nullptr, nullptr, nullptr);
    convT_kernel<<<dim3(CDIM / 32, (4 * CDIM) / 32), blk, 0, stream>>>(
        fcproj_w + (size_t)l * 4 * CDIM * CDIM, Wt, 4 * CDIM, CDIM);
    gemm_kernel<2><<<dim3((CDIM / 128) * 16), blk, 0, stream>>>(
        hb, Wt, fcproj_b + l * CDIM, 4 * CDIM, CDIM,
        x, nullptr, nullptr, nullptr, nullptr);
  }

  ln_kernel<<<MROWS, blk, 0, stream>>>(x, lnf_w, lnf_b, xb);
  convT_kernel<<<dim3((VOCAB + 31) / 32, CDIM / 32), blk, 0, stream>>>(
      lm_head_w, Wt, CDIM, VOCAB);
  gemm_kernel<4><<<dim3(((VOCAB + 127) / 128) * 16), blk, 0, stream>>>(
      xb, Wt, nullptr, CDIM, VOCAB,
      out, nullptr, nullptr, nullptr, nullptr);
}